// Round 5
// baseline (294.067 us; speedup 1.0000x reference)
//
#include <hip/hip_runtime.h>

// KPN per-pixel dynamic kernel conv.
// data:    [1, 8, 3, 96, 96]        fp32 (~0.9 MB, cache-resident)
// kernels: [1, 8, 225, 3, 96, 96]   fp32 (199 MB streaming read)
// out:     [1, 8, 3, 96, 96]        fp32
// out[t,c,h,w] = sum_{i,j} kernels[t,i*15+j,c,h,w] * data[t,c,h+i-7,w+j-7] (zero pad)
//
// Round 5: long contiguous per-wave streams + nontemporal loads/stores.
//  - wave = 16x96 slab of one (t,c) plane, 25-tap k-group -> 1296 waves
//  - per tap: 6 KiB sequential read (6 dwordx4/lane), double-buffered
//  - nt loads/stores keep the 199 MB stream out of L2/L3 (avoids evicting
//    the harness's dirty 796 MB poison back to HBM)
// No LDS / barriers / atomics -> deterministic across graph replays.

typedef float vf4 __attribute__((ext_vector_type(4)));

constexpr int K  = 15;
constexpr int P  = 7;
constexpr int H  = 96;
constexpr int W  = 96;
constexpr int C  = 3;
constexpr int T  = 8;
constexpr int HW = H * W;              // 9216
constexpr int K2 = K * K;              // 225
constexpr int NP = T * C;              // 24 planes
constexpr int NE = NP * HW;            // 221184
constexpr size_t CHW = (size_t)C * HW; // 27648 floats between taps
constexpr int SR   = 16;               // slab rows per wave
constexpr int SPP  = H / SR;           // 6 slabs per plane
constexpr int TILES = NP * SPP;        // 144 spatial tiles
constexpr int KGRP = 9;                // k split into 9 groups
constexpr int KPG  = 25;               // taps per group (9*25 = 225)
constexpr int NWAVES = TILES * KGRP;   // 1296 one-wave blocks
constexpr int QL = (SR * W) / (64 * 4);// 6 float4 per lane per tap
constexpr size_t PART_BYTES = (size_t)KGRP * NE * 4;   // 7.96 MB

__device__ __forceinline__ vf4 nt4(const float* p) {
    return __builtin_nontemporal_load(reinterpret_cast<const vf4*>(p));
}

__global__ __launch_bounds__(64) void kpn_part(
    const float* __restrict__ data,
    const float* __restrict__ kern,
    float* __restrict__ part)
{
    const int lane = threadIdx.x;          // 0..63
    const int w    = blockIdx.x;           // 0..1295
    const int kg   = w / TILES;
    const int tile = w % TILES;
    const int plane = tile / SPP;          // t*C + c
    const int s     = tile % SPP;
    const int t  = plane / C;
    const int c  = plane % C;
    const int r0 = s * SR;

    // lane's 6 quads inside the 16x96 slab: flat = (q*64+lane)*4
    int qrow[QL], qcol[QL];
    #pragma unroll
    for (int q = 0; q < QL; ++q) {
        const int flat = (q * 64 + lane) * 4;
        qrow[q] = flat / W;
        qcol[q] = flat % W;
    }

    const float* __restrict__ dpl = data + plane * HW;
    const float* __restrict__ kbase =
        kern + (size_t)(t * K2) * CHW + (size_t)c * HW + (size_t)r0 * W + lane * 4;
    const int k0 = kg * KPG;

    float acc[QL][4];
    #pragma unroll
    for (int q = 0; q < QL; ++q)
        #pragma unroll
        for (int e = 0; e < 4; ++e) acc[q][e] = 0.f;

    auto load_stage = [&](vf4 (&buf)[QL], int k) {
        const float* p = kbase + (size_t)k * CHW;
        #pragma unroll
        for (int q = 0; q < QL; ++q) buf[q] = nt4(p + q * 256);
    };

    auto consume = [&](vf4 (&buf)[QL], int k) {
        const int i = k / K;
        const int j = k % K;
        #pragma unroll
        for (int q = 0; q < QL; ++q) {
            const int sr  = r0 + qrow[q] + i - P;
            const bool rv = (sr >= 0) && (sr < H);
            const float* __restrict__ drow = dpl + (rv ? sr : 0) * W;
            #pragma unroll
            for (int e = 0; e < 4; ++e) {
                const int sc  = qcol[q] + e + j - P;
                const bool cv = rv && (sc >= 0) && (sc < W);
                const int scc = (sc < 0) ? 0 : ((sc >= W) ? (W - 1) : sc);
                const float dv = drow[scc];          // address always in-bounds
                acc[q][e] += buf[q][e] * (cv ? dv : 0.f);
            }
        }
    };

    vf4 A[QL], B[QL];
    load_stage(A, k0);
    #pragma unroll 1
    for (int u = 0; u < KPG - 1; u += 2) {          // u = 0,2,...,22
        load_stage(B, k0 + u + 1);
        consume(A, k0 + u);
        load_stage(A, k0 + u + 2);                  // u+2 <= 24: always valid
        consume(B, k0 + u + 1);
    }
    consume(A, k0 + KPG - 1);

    float* pp = part + (size_t)kg * NE + (size_t)plane * HW
                     + (size_t)r0 * W + lane * 4;
    #pragma unroll
    for (int q = 0; q < QL; ++q) {
        vf4 v = { acc[q][0], acc[q][1], acc[q][2], acc[q][3] };
        __builtin_nontemporal_store(v, reinterpret_cast<vf4*>(pp + q * 256));
    }
}

__global__ __launch_bounds__(256) void kpn_reduce(
    const float* __restrict__ part, float* __restrict__ out)
{
    const int e4 = blockIdx.x * 256 + threadIdx.x;   // 0..NE/4-1
    const float* p = part + (size_t)e4 * 4;
    vf4 sum = {0.f, 0.f, 0.f, 0.f};
    #pragma unroll
    for (int g = 0; g < KGRP; ++g) {
        sum += nt4(p + (size_t)g * NE);
    }
    __builtin_nontemporal_store(sum, reinterpret_cast<vf4*>(out + (size_t)e4 * 4));
}

// Fallback if d_ws too small: fused, correct, slower.
__global__ __launch_bounds__(256, 4) void kpn_fused(
    const float* __restrict__ data,
    const float* __restrict__ kern,
    float* __restrict__ out)
{
    const int gq   = blockIdx.x * 256 + threadIdx.x;   // quad id 0..55295
    const int w4   = gq % (W / 4);
    const int rem  = gq / (W / 4);
    const int h    = rem % H;
    const int plane = rem / H;
    const int t = plane / C;
    const int c = plane % C;
    const int col = w4 * 4;

    float4 acc = make_float4(0.f, 0.f, 0.f, 0.f);
    for (int i = 0; i < K; ++i) {
        const float* __restrict__ kptr =
            kern + ((size_t)((t * K2 + i * K) * C + c)) * HW + (size_t)h * W + col;
        float4 kv[K];
        #pragma unroll
        for (int j = 0; j < K; ++j)
            kv[j] = *reinterpret_cast<const float4*>(kptr + (size_t)j * CHW);

        const int srow = h + i - P;
        const bool rv  = (srow >= 0) && (srow < H);
        const float* __restrict__ drow = data + plane * HW + (rv ? srow : 0) * W;
        float dwin[K + 3];
        #pragma unroll
        for (int m = 0; m < K + 3; ++m) {
            const int cc  = col - P + m;
            const int ccc = (cc < 0) ? 0 : ((cc >= W) ? (W - 1) : cc);
            const float v = drow[ccc];
            dwin[m] = (rv && cc >= 0 && cc < W) ? v : 0.f;
        }
        #pragma unroll
        for (int j = 0; j < K; ++j) {
            acc.x += kv[j].x * dwin[j + 0];
            acc.y += kv[j].y * dwin[j + 1];
            acc.z += kv[j].z * dwin[j + 2];
            acc.w += kv[j].w * dwin[j + 3];
        }
    }
    float* op = out + (size_t)plane * HW + (size_t)h * W + col;
    *reinterpret_cast<float4*>(op) = acc;
}

extern "C" void kernel_launch(void* const* d_in, const int* in_sizes, int n_in,
                              void* d_out, int out_size, void* d_ws, size_t ws_size,
                              hipStream_t stream) {
    const float* data = (const float*)d_in[0];
    const float* kern = (const float*)d_in[1];
    float* out        = (float*)d_out;

    if (ws_size >= PART_BYTES) {
        float* part = (float*)d_ws;
        hipLaunchKernelGGL(kpn_part, dim3(NWAVES), dim3(64), 0, stream,
                           data, kern, part);
        hipLaunchKernelGGL(kpn_reduce, dim3(NE / 4 / 256), dim3(256), 0, stream,
                           part, out);
    } else {
        hipLaunchKernelGGL(kpn_fused, dim3(NE / 4 / 256), dim3(256), 0, stream,
                           data, kern, out);
    }
}

// Round 6
// 275.313 us; speedup vs baseline: 1.0681x; 1.0681x over previous
//
#include <hip/hip_runtime.h>

// KPN per-pixel dynamic kernel conv.
// data:    [1, 8, 3, 96, 96]        fp32 (~0.9 MB)
// kernels: [1, 8, 225, 3, 96, 96]   fp32 (199 MB streaming read, used once)
// out:     [1, 8, 3, 96, 96]        fp32
// out[t,c,h,w] = sum_{i,j} kernels[t,i*15+j,c,h,w] * data[t,c,h+i-7,w+j-7] (zero pad)
//
// Round 6: single fused kernel (no partials / no reduce launch), nontemporal
// kernel-stream loads (no L2/L3 allocation -> no dirty-poison write-backs),
// tap-row double-buffering (15 NT dwordx4 in flight while previous row FMAs).
// 864 one-wave blocks (~3.4 waves/CU; 0.85/SIMD -> VGPR pressure irrelevant).
// No LDS / barriers / atomics -> bit-deterministic across graph replays.

typedef float vf4 __attribute__((ext_vector_type(4)));

constexpr int K  = 15;
constexpr int P  = 7;
constexpr int H  = 96;
constexpr int W  = 96;
constexpr int C  = 3;
constexpr int T  = 8;
constexpr int HW = H * W;              // 9216
constexpr int K2 = K * K;              // 225
constexpr int NP = T * C;              // 24 planes
constexpr int NE = NP * HW;            // 221184 output elems
constexpr size_t CHW = (size_t)C * HW; // 27648 floats between consecutive taps
constexpr int NQ   = NE / 4;           // 55296 quads
constexpr int BLK  = 64;               // one wave per block
constexpr int NBLK = NQ / BLK;         // 864 blocks

__device__ __forceinline__ vf4 nt4(const float* p) {
    return __builtin_nontemporal_load(reinterpret_cast<const vf4*>(p));
}

__global__ __launch_bounds__(BLK) void kpn_fused_nt(
    const float* __restrict__ data,
    const float* __restrict__ kern,
    float* __restrict__ out)
{
    const int q     = blockIdx.x * BLK + threadIdx.x;   // quad id
    const int w4    = q % (W / 4);
    const int rem   = q / (W / 4);
    const int h     = rem % H;
    const int plane = rem / H;          // t*C + c
    const int t     = plane / C;
    const int c     = plane % C;
    const int col   = w4 * 4;

    // tap (i,j) lives at kbase + (i*K + j)*CHW
    const float* __restrict__ kbase =
        kern + ((size_t)(t * K2) * C + (size_t)c) * HW + (size_t)h * W + col;
    const float* __restrict__ dpl = data + plane * HW;

    // Column clamp/validity is row-independent: precompute once.
    int  colc[K + 3];
    bool cval[K + 3];
    #pragma unroll
    for (int m = 0; m < K + 3; ++m) {
        const int cc = col - P + m;
        cval[m] = (cc >= 0) && (cc < W);
        colc[m] = (cc < 0) ? 0 : ((cc >= W) ? (W - 1) : cc);
    }

    float acc[4] = {0.f, 0.f, 0.f, 0.f};

    auto load_row = [&](vf4 (&buf)[K], int i) {
        const float* p = kbase + (size_t)(i * K) * CHW;
        #pragma unroll
        for (int j = 0; j < K; ++j) buf[j] = nt4(p + (size_t)j * CHW);
    };

    auto consume_row = [&](vf4 (&buf)[K], int i) {
        const int srow = h + i - P;
        const bool rv  = (srow >= 0) && (srow < H);
        const float* __restrict__ drow = dpl + (rv ? srow : 0) * W;
        float dwin[K + 3];
        #pragma unroll
        for (int m = 0; m < K + 3; ++m) {
            const float v = drow[colc[m]];           // address always in-bounds
            dwin[m] = (rv && cval[m]) ? v : 0.f;
        }
        #pragma unroll
        for (int j = 0; j < K; ++j) {
            acc[0] += buf[j][0] * dwin[j + 0];
            acc[1] += buf[j][1] * dwin[j + 1];
            acc[2] += buf[j][2] * dwin[j + 2];
            acc[3] += buf[j][3] * dwin[j + 3];
        }
    };

    vf4 A[K], B[K];
    load_row(A, 0);
    #pragma unroll 1
    for (int i = 0; i < K - 1; i += 2) {     // i = 0,2,...,12
        load_row(B, i + 1);
        consume_row(A, i);
        load_row(A, i + 2);                  // i+2 <= 14: always a valid row
        consume_row(B, i + 1);
    }
    consume_row(A, K - 1);

    vf4 o = { acc[0], acc[1], acc[2], acc[3] };
    float* op = out + (size_t)plane * HW + (size_t)h * W + col;
    __builtin_nontemporal_store(o, reinterpret_cast<vf4*>(op));
}

extern "C" void kernel_launch(void* const* d_in, const int* in_sizes, int n_in,
                              void* d_out, int out_size, void* d_ws, size_t ws_size,
                              hipStream_t stream) {
    const float* data = (const float*)d_in[0];
    const float* kern = (const float*)d_in[1];
    float* out        = (float*)d_out;
    hipLaunchKernelGGL(kpn_fused_nt, dim3(NBLK), dim3(BLK), 0, stream,
                       data, kern, out);
}